// Round 2
// baseline (921.215 us; speedup 1.0000x reference)
//
#include <hip/hip_runtime.h>
#include <math.h>

#define B 32
#define C 256
#define HW 1024

// ---------------- Kernel 1: reciprocal channel norms ----------------
// rnorm[b][q] = 1 / max(sqrt(sum_c x[b][c][q]^2), 1e-8)
__global__ __launch_bounds__(256) void norms_kernel(const float* __restrict__ x,
                                                    float* __restrict__ rnorm) {
    const int q = blockIdx.x * 256 + threadIdx.x;
    const int b = blockIdx.y;
    const float* xb = x + (size_t)b * C * HW + q;
    float s = 0.f;
#pragma unroll 8
    for (int c = 0; c < C; ++c) {
        float v = xb[(size_t)c * HW];
        s += v * v;
    }
    float n = fmaxf(sqrtf(s), 1e-8f);
    rnorm[b * HW + q] = 1.f / n;
}

// ---------------- Kernel 2: t = W * X + bias, stored transposed t_ws[b][k][c] ----
#define TGO 64
#define TGK 64
#define TGC 32

__global__ __launch_bounds__(256) void tgemm_kernel(const float* __restrict__ x,
                                                    const float* __restrict__ w,
                                                    const float* __restrict__ bias,
                                                    float* __restrict__ t_ws) {
    __shared__ float Wt[TGC][TGO + 1];  // [cc][oo]  (+1 pad: conflict-free scalar access)
    __shared__ float Xt[TGC][TGK + 1];  // [cc][kk]
    const int tid = threadIdx.x;
    const int b = blockIdx.z;
    const int o0 = blockIdx.y * TGO;
    const int k0 = blockIdx.x * TGK;
    const int to = tid & 15;   // o index fastest across lanes
    const int tk = tid >> 4;   // 0..15
    const float* xb = x + (size_t)b * C * HW;
    float acc[4][4] = {};  // [i -> o0+to+16i][j -> k0+tk+16j]
    for (int c0 = 0; c0 < C; c0 += TGC) {
        __syncthreads();
        {
            int cc = tid & 31, oo0 = tid >> 5;
#pragma unroll
            for (int m = 0; m < 8; ++m) {
                int oo = oo0 + m * 8;
                Wt[cc][oo] = w[(o0 + oo) * C + c0 + cc];  // coalesced along c
            }
        }
        {
            int kk = tid & 63, cc0 = tid >> 6;
#pragma unroll
            for (int m = 0; m < 8; ++m) {
                int cc = cc0 + m * 4;
                Xt[cc][kk] = xb[(size_t)(c0 + cc) * HW + k0 + kk];  // coalesced along k
            }
        }
        __syncthreads();
#pragma unroll
        for (int cc = 0; cc < TGC; ++cc) {
            float wv[4], xv[4];
#pragma unroll
            for (int i = 0; i < 4; ++i) wv[i] = Wt[cc][to + 16 * i];   // 16 uniq addrs, 16 banks
#pragma unroll
            for (int j = 0; j < 4; ++j) xv[j] = Xt[cc][tk + 16 * j];   // 4 uniq -> broadcast
#pragma unroll
            for (int i = 0; i < 4; ++i)
#pragma unroll
                for (int j = 0; j < 4; ++j) acc[i][j] += wv[i] * xv[j];
        }
    }
    float bb[4];
#pragma unroll
    for (int i = 0; i < 4; ++i) bb[i] = bias[o0 + to + 16 * i];
    float* tb = t_ws + (size_t)b * HW * C;
#pragma unroll
    for (int j = 0; j < 4; ++j) {
        int k = k0 + tk + 16 * j;
#pragma unroll
        for (int i = 0; i < 4; ++i) {
            // lanes 0..15 write consecutive o -> 64B segments, 4 rows per wave instr
            tb[(size_t)k * C + o0 + to + 16 * i] = acc[i][j] + bb[i];
        }
    }
}

// ---------------- Kernel 3: fused sim (relu^2 of cosine Gram) + aggregation ----
// Per block: batch b, 128-wide q tile. out[c][q] = sum_k relu(xn_q . xn_k)^2 * t[c][k]
#define QT 128
#define KT 128
#define CCH 32

struct SMemA {
    float xq[CCH][QT];  // 16 KiB, normalized
    float xk[CCH][KT];  // 16 KiB, normalized
};
union SMemU {
    SMemA a;
    float T[KT][128];   // 64 KiB: T chunk [kk][c within 128-chunk]
};

__global__ __launch_bounds__(256, 1) void fused_kernel(const float* __restrict__ x,
                                                       const float* __restrict__ rnorm,
                                                       const float* __restrict__ t_ws,
                                                       float* __restrict__ out) {
    __shared__ SMemU sm;          // 64 KiB (staging buffers aliased with T chunk)
    __shared__ float S[KT * QT];  // 64 KiB, stored transposed: S[k*QT + q]
    const int tid = threadIdx.x;
    const int b = blockIdx.y;
    const int qg0 = blockIdx.x * QT;
    const float* xb = x + (size_t)b * C * HW;
    const float* rb = rnorm + b * HW;
    const float* tb = t_ws + (size_t)b * HW * C;

    const int col4 = tid & 31;  // float4 column for staging (32 float4 = 128 floats)
    const int srow = tid >> 5;  // 0..7

    const int tq = tid & 15;    // q micro-group
    const int tg = tid >> 4;    // k micro-group (phase A) / c micro-group (phase B)
    const int q0 = tq * 8;
    const int g0 = tg * 8;

    const float4 rq4 = ((const float4*)(rb + qg0))[col4];

    float out_acc[2][8][8] = {};  // [c half][c_i][q_j] -- 128 persistent VGPRs

    for (int kt = 0; kt < 8; ++kt) {
        const int kg0 = kt * KT;
        const float4 rk4 = ((const float4*)(rb + kg0))[col4];
        float s_acc[8][8] = {};  // [q_i][k_j]

        // ---- Phase A: S = Xn_q^T * Xn_k over 8 c-chunks of 32 ----
        for (int cch = 0; cch < 8; ++cch) {
            const int c0 = cch * CCH;
            __syncthreads();  // prior consumers of sm.a / sm.T done
#pragma unroll
            for (int m = 0; m < 4; ++m) {
                int cc = srow + m * 8;
                float4 vq = ((const float4*)(xb + (size_t)(c0 + cc) * HW + qg0))[col4];
                vq.x *= rq4.x; vq.y *= rq4.y; vq.z *= rq4.z; vq.w *= rq4.w;
                ((float4*)&sm.a.xq[cc][0])[col4] = vq;
                float4 vk = ((const float4*)(xb + (size_t)(c0 + cc) * HW + kg0))[col4];
                vk.x *= rk4.x; vk.y *= rk4.y; vk.z *= rk4.z; vk.w *= rk4.w;
                ((float4*)&sm.a.xk[cc][0])[col4] = vk;
            }
            __syncthreads();
#pragma unroll 2
            for (int cc = 0; cc < CCH; ++cc) {
                const float4 a0 = *(const float4*)&sm.a.xq[cc][q0];
                const float4 a1 = *(const float4*)&sm.a.xq[cc][q0 + 4];
                const float4 b0 = *(const float4*)&sm.a.xk[cc][g0];
                const float4 b1 = *(const float4*)&sm.a.xk[cc][g0 + 4];
                const float av[8] = {a0.x, a0.y, a0.z, a0.w, a1.x, a1.y, a1.z, a1.w};
                const float bv[8] = {b0.x, b0.y, b0.z, b0.w, b1.x, b1.y, b1.z, b1.w};
#pragma unroll
                for (int i = 0; i < 8; ++i)
#pragma unroll
                    for (int j = 0; j < 8; ++j) s_acc[i][j] += av[i] * bv[j];
            }
        }

        // ---- relu^2, write S transposed S[k][q] (prev phase B readers synced long ago)
#pragma unroll
        for (int j = 0; j < 8; ++j) {
            float tmp[8];
#pragma unroll
            for (int i = 0; i < 8; ++i) {
                float sv = fmaxf(s_acc[i][j], 0.f);
                tmp[i] = sv * sv;
            }
            *(float4*)&S[(g0 + j) * QT + q0]     = make_float4(tmp[0], tmp[1], tmp[2], tmp[3]);
            *(float4*)&S[(g0 + j) * QT + q0 + 4] = make_float4(tmp[4], tmp[5], tmp[6], tmp[7]);
        }
        __syncthreads();

        // ---- Phase B: out_acc += T_chunk * S^T, two 128-c halves ----
#pragma unroll
        for (int cb = 0; cb < 2; ++cb) {
#pragma unroll
            for (int m = 0; m < 16; ++m) {
                int kk = srow + m * 8;
                float4 v = ((const float4*)(tb + (size_t)(kg0 + kk) * C + cb * 128))[col4];
                ((float4*)&sm.T[kk][0])[col4] = v;  // rows contiguous in c: conflict-free
            }
            __syncthreads();
#pragma unroll 2
            for (int k = 0; k < KT; ++k) {
                const float4 t0 = *(const float4*)&sm.T[k][g0];
                const float4 t1 = *(const float4*)&sm.T[k][g0 + 4];
                const float4 s0 = *(const float4*)&S[k * QT + q0];
                const float4 s1 = *(const float4*)&S[k * QT + q0 + 4];
                const float tv[8] = {t0.x, t0.y, t0.z, t0.w, t1.x, t1.y, t1.z, t1.w};
                const float sv[8] = {s0.x, s0.y, s0.z, s0.w, s1.x, s1.y, s1.z, s1.w};
#pragma unroll
                for (int i = 0; i < 8; ++i)
#pragma unroll
                    for (int j = 0; j < 8; ++j) out_acc[cb][i][j] += tv[i] * sv[j];
            }
            __syncthreads();
        }
    }

    // ---- epilogue: out[b][c][qg0+q] ----
#pragma unroll
    for (int cb = 0; cb < 2; ++cb)
#pragma unroll
        for (int i = 0; i < 8; ++i) {
            int c = cb * 128 + g0 + i;
            float* ob = out + ((size_t)b * C + c) * HW + qg0 + q0;
            *(float4*)&ob[0] = make_float4(out_acc[cb][i][0], out_acc[cb][i][1],
                                           out_acc[cb][i][2], out_acc[cb][i][3]);
            *(float4*)&ob[4] = make_float4(out_acc[cb][i][4], out_acc[cb][i][5],
                                           out_acc[cb][i][6], out_acc[cb][i][7]);
        }
}

extern "C" void kernel_launch(void* const* d_in, const int* in_sizes, int n_in,
                              void* d_out, int out_size, void* d_ws, size_t ws_size,
                              hipStream_t stream) {
    const float* x    = (const float*)d_in[0];  // (32,256,32,32)
    const float* w    = (const float*)d_in[1];  // (256,256)
    const float* bias = (const float*)d_in[2];  // (256,)
    float* out = (float*)d_out;

    // ws layout: rnorm (B*HW floats = 128 KiB) | t_ws (B*HW*C floats = 32 MiB)
    float* rnorm = (float*)d_ws;
    float* t_ws  = rnorm + B * HW;

    hipLaunchKernelGGL(norms_kernel, dim3(HW / 256, B), dim3(256), 0, stream, x, rnorm);
    hipLaunchKernelGGL(tgemm_kernel, dim3(HW / TGK, C / TGO, B), dim3(256), 0, stream,
                       x, w, bias, t_ws);
    hipLaunchKernelGGL(fused_kernel, dim3(HW / QT, B), dim3(256), 0, stream,
                       x, rnorm, t_ws, out);
}

// Round 3
// 109.692 us; speedup vs baseline: 8.3982x; 8.3982x over previous
//
#include <hip/hip_runtime.h>
#include <math.h>

#define B 32
#define C 256
#define HW 1024

typedef __attribute__((ext_vector_type(8))) short bf16x8;
typedef __attribute__((ext_vector_type(4))) float f32x4;

__device__ __forceinline__ unsigned short f2bf(float f) {
    unsigned int u = __float_as_uint(f);
    u += 0x7fffu + ((u >> 16) & 1u);  // RNE (values are normal floats here)
    return (unsigned short)(u >> 16);
}

__device__ __forceinline__ void gload16(const void* g, void* l) {
    __builtin_amdgcn_global_load_lds(
        (const __attribute__((address_space(1))) unsigned int*)g,
        (__attribute__((address_space(3))) unsigned int*)l, 16, 0, 0);
}

// ---------------- Kernel 1: reciprocal channel norms (fp32) ----------------
__global__ __launch_bounds__(256) void norms_kernel(const float* __restrict__ x,
                                                    float* __restrict__ rnorm) {
    const int q = blockIdx.x * 256 + threadIdx.x;
    const int b = blockIdx.y;
    const float* xb = x + (size_t)b * C * HW + q;
    float s = 0.f;
#pragma unroll 8
    for (int c = 0; c < C; ++c) {
        float v = xb[(size_t)c * HW];
        s += v * v;
    }
    float n = fmaxf(sqrtf(s), 1e-8f);
    rnorm[b * HW + q] = 1.f / n;
}

// ---------------- Kernel 2: cast W to bf16 ----------------
__global__ __launch_bounds__(256) void castw_kernel(const float* __restrict__ w,
                                                    unsigned short* __restrict__ wb) {
    int i = (blockIdx.x * 256 + threadIdx.x) * 4;
    float4 v = *(const float4*)(w + i);
    unsigned long long pk = (unsigned long long)f2bf(v.x) |
                            ((unsigned long long)f2bf(v.y) << 16) |
                            ((unsigned long long)f2bf(v.z) << 32) |
                            ((unsigned long long)f2bf(v.w) << 48);
    *(unsigned long long*)(wb + i) = pk;
}

// ---------------- Kernel 3: transpose + normalize + bf16 cast ----------------
// x[b][c][q] -> xT[b][q][c] (bf16), xnT[b][q][c] (bf16, * rnorm[q])
__global__ __launch_bounds__(256) void prep_kernel(const float* __restrict__ x,
                                                   const float* __restrict__ rnorm,
                                                   unsigned short* __restrict__ xT,
                                                   unsigned short* __restrict__ xnT) {
    __shared__ float tile[64][65];
    const int t = threadIdx.x;
    const int q0 = blockIdx.x * 64, c0 = blockIdx.y * 64, b = blockIdx.z;
    const float* xb = x + ((size_t)b * C + c0) * HW + q0;
#pragma unroll
    for (int p = 0; p < 16; ++p) {
        int cc = p * 4 + (t >> 6);
        int qq = t & 63;
        tile[cc][qq] = xb[(size_t)cc * HW + qq];
    }
    __syncthreads();
    const float* rb = rnorm + b * HW + q0;
#pragma unroll
    for (int p = 0; p < 16; ++p) {
        int qq = p * 4 + (t >> 6);
        int cc = t & 63;
        float v = tile[cc][qq];
        float rn = rb[qq];
        size_t o = ((size_t)b * HW + q0 + qq) * C + c0 + cc;
        xT[o] = f2bf(v);
        xnT[o] = f2bf(v * rn);
    }
}

// ---------------- MFMA gemm_bt core: C[m][n] = sum_k A[m][k] * B[n][k] -------
// 128x128 tile, 4 waves (2x2), 16x16x32 bf16 MFMA, BK=64, single-buffered LDS,
// global_load_lds w=16 staging with involutive XOR-swizzle on 16B units (T2).
// MODE 0: +bias[m], bf16 store.  MODE 1: relu()^2, bf16 store.  MODE 2: fp32 store.
template <int KSTEPS, int MODE>
__global__ __launch_bounds__(256) void gemm_bt_kernel(
    const unsigned short* __restrict__ A, long strideAb, int ldA,
    const unsigned short* __restrict__ Bm, long strideBb, int ldB,
    void* __restrict__ Cv, long strideCb, int ldC,
    const float* __restrict__ bias) {
    __shared__ unsigned short Asub[128 * 64];  // 16 KiB, rows of 128 B
    __shared__ unsigned short Bsub[128 * 64];  // 16 KiB
    const int t = threadIdx.x;
    const int bz = blockIdx.z;
    const int m0 = blockIdx.y * 128, n0 = blockIdx.x * 128;

    // staging: thread t -> row (t>>3) (+32/pass), 16B-unit slot (t&7),
    // source unit = slot ^ (row&7)  (involution; LDS dest stays linear t*16)
    const int ug = ((t & 7) ^ ((t >> 3) & 7)) * 16;
    const char* gA = (const char*)(A + (size_t)strideAb * bz) +
                     (size_t)(m0 + (t >> 3)) * (ldA * 2) + ug;
    const char* gB = (const char*)(Bm + (size_t)strideBb * bz) +
                     (size_t)(n0 + (t >> 3)) * (ldB * 2) + ug;
    char* lA = (char*)Asub + t * 16;
    char* lB = (char*)Bsub + t * 16;
    const int rowStepA = 32 * ldA * 2, rowStepB = 32 * ldB * 2;

    // fragment addressing
    const int lane = t & 63;
    const int wid = t >> 6;
    const int wr = wid >> 1, wc = wid & 1;   // 2x2 waves over the 128x128 tile
    const int lr = lane & 15, hi = lane >> 4;
    int rowA[4], rowB[4], sb[2];
#pragma unroll
    for (int i = 0; i < 4; ++i) rowA[i] = (wr * 64 + i * 16 + lr) * 128;
#pragma unroll
    for (int j = 0; j < 4; ++j) rowB[j] = (wc * 64 + j * 16 + lr) * 128;
#pragma unroll
    for (int kk = 0; kk < 2; ++kk) sb[kk] = ((hi + 4 * kk) ^ (lr & 7)) * 16;

    f32x4 acc[4][4];
#pragma unroll
    for (int i = 0; i < 4; ++i)
#pragma unroll
        for (int j = 0; j < 4; ++j) acc[i][j] = (f32x4)(0.f);

#pragma unroll
    for (int p = 0; p < 4; ++p) {  // stage K-step 0
        gload16(gA + p * rowStepA, lA + p * 4096);
        gload16(gB + p * rowStepB, lB + p * 4096);
    }

    for (int ks = 0; ks < KSTEPS; ++ks) {
        __syncthreads();  // compiler drains vmcnt before s_barrier
#pragma unroll
        for (int kk = 0; kk < 2; ++kk) {
            bf16x8 av[4], bv[4];
#pragma unroll
            for (int i = 0; i < 4; ++i)
                av[i] = *(const bf16x8*)((const char*)Asub + rowA[i] + sb[kk]);
#pragma unroll
            for (int j = 0; j < 4; ++j)
                bv[j] = *(const bf16x8*)((const char*)Bsub + rowB[j] + sb[kk]);
#pragma unroll
            for (int i = 0; i < 4; ++i)
#pragma unroll
                for (int j = 0; j < 4; ++j)
                    acc[i][j] = __builtin_amdgcn_mfma_f32_16x16x32_bf16(
                        av[i], bv[j], acc[i][j], 0, 0, 0);
        }
        __syncthreads();
        if (ks + 1 < KSTEPS) {
            const char* gA2 = gA + (size_t)(ks + 1) * 128;  // 64 bf16 = 128 B per K-step
            const char* gB2 = gB + (size_t)(ks + 1) * 128;
#pragma unroll
            for (int p = 0; p < 4; ++p) {
                gload16(gA2 + p * rowStepA, lA + p * 4096);
                gload16(gB2 + p * rowStepB, lB + p * 4096);
            }
        }
    }

    // epilogue: C row = m0+wr*64+i*16+hi*4+r, col = n0+wc*64+j*16+lr
    const int mb = m0 + wr * 64 + hi * 4;
    const int nb = n0 + wc * 64 + lr;
    if (MODE == 0) {
        unsigned short* Cp = (unsigned short*)Cv + (size_t)strideCb * bz;
#pragma unroll
        for (int i = 0; i < 4; ++i)
#pragma unroll
            for (int r = 0; r < 4; ++r) {
                int m = mb + i * 16 + r;
                float bbv = bias[m];
#pragma unroll
                for (int j = 0; j < 4; ++j)
                    Cp[(size_t)m * ldC + nb + j * 16] = f2bf(acc[i][j][r] + bbv);
            }
    } else if (MODE == 1) {
        unsigned short* Cp = (unsigned short*)Cv + (size_t)strideCb * bz;
#pragma unroll
        for (int i = 0; i < 4; ++i)
#pragma unroll
            for (int r = 0; r < 4; ++r) {
                int m = mb + i * 16 + r;
#pragma unroll
                for (int j = 0; j < 4; ++j) {
                    float v = fmaxf(acc[i][j][r], 0.f);
                    Cp[(size_t)m * ldC + nb + j * 16] = f2bf(v * v);
                }
            }
    } else {
        float* Cp = (float*)Cv + (size_t)strideCb * bz;
#pragma unroll
        for (int i = 0; i < 4; ++i)
#pragma unroll
            for (int r = 0; r < 4; ++r) {
                int m = mb + i * 16 + r;
#pragma unroll
                for (int j = 0; j < 4; ++j)
                    Cp[(size_t)m * ldC + nb + j * 16] = acc[i][j][r];
            }
    }
}

extern "C" void kernel_launch(void* const* d_in, const int* in_sizes, int n_in,
                              void* d_out, int out_size, void* d_ws, size_t ws_size,
                              hipStream_t stream) {
    const float* x    = (const float*)d_in[0];  // (32,256,32,32)
    const float* w    = (const float*)d_in[1];  // (256,256)
    const float* bias = (const float*)d_in[2];  // (256,)
    float* out = (float*)d_out;

    // ws: rnorm 128K | wbf 128K | xT 16M | xnT 16M | t 16M | sim 64M  = 112.25 MiB
    char* ws = (char*)d_ws;
    float* rnorm        = (float*)ws;
    unsigned short* wbf = (unsigned short*)(ws + (128 << 10));
    unsigned short* xT  = (unsigned short*)(ws + (256 << 10));
    unsigned short* xnT = (unsigned short*)(ws + (256 << 10) + (16u << 20));
    unsigned short* tb  = (unsigned short*)(ws + (256 << 10) + (32u << 20));
    unsigned short* simb= (unsigned short*)(ws + (256 << 10) + (48u << 20));

    hipLaunchKernelGGL(norms_kernel, dim3(HW / 256, B), dim3(256), 0, stream, x, rnorm);
    hipLaunchKernelGGL(castw_kernel, dim3(C * C / 1024), dim3(256), 0, stream, w, wbf);
    hipLaunchKernelGGL(prep_kernel, dim3(HW / 64, C / 64, B), dim3(256), 0, stream,
                       x, rnorm, xT, xnT);
    // t[b][o][k] = sum_c W[o][c] * xT[b][k][c] + bias
    hipLaunchKernelGGL((gemm_bt_kernel<4, 0>), dim3(HW / 128, C / 128, B), dim3(256), 0,
                       stream, wbf, 0L, C, xT, (long)HW * C, C, tb, (long)C * HW, HW, bias);
    // sim[b][q][k] = relu(sum_c xnT[b][q][c] * xnT[b][k][c])^2
    hipLaunchKernelGGL((gemm_bt_kernel<4, 1>), dim3(HW / 128, HW / 128, B), dim3(256), 0,
                       stream, xnT, (long)HW * C, C, xnT, (long)HW * C, C,
                       simb, (long)HW * HW, HW, (const float*)nullptr);
    // out[b][c][q] = sum_k t[b][c][k] * sim[b][q][k]   (fp32)
    hipLaunchKernelGGL((gemm_bt_kernel<16, 2>), dim3(HW / 128, C / 128, B), dim3(256), 0,
                       stream, tb, (long)C * HW, HW, simb, (long)HW * HW, HW,
                       out, (long)C * HW, HW, (const float*)nullptr);
}

// Round 7
// 95.480 us; speedup vs baseline: 9.6482x; 1.1488x over previous
//
#include <hip/hip_runtime.h>
#include <math.h>

#define B 32
#define C 256
#define HW 1024

typedef __attribute__((ext_vector_type(8))) short bf16x8;
typedef __attribute__((ext_vector_type(4))) float f32x4;

__device__ __forceinline__ unsigned short f2bf(float f) {
    unsigned int u = __float_as_uint(f);
    u += 0x7fffu + ((u >> 16) & 1u);  // RNE
    return (unsigned short)(u >> 16);
}

__device__ __forceinline__ void gload16(const void* g, void* l) {
    __builtin_amdgcn_global_load_lds(
        (const __attribute__((address_space(1))) unsigned int*)g,
        (__attribute__((address_space(3))) unsigned int*)l, 16, 0, 0);
}

// ---------------- Kernel 1: channel norms (fp32): norm and 1/norm ------------
__global__ __launch_bounds__(256) void norms_kernel(const float* __restrict__ x,
                                                    float* __restrict__ norm,
                                                    float* __restrict__ rnorm) {
    const int q = blockIdx.x * 256 + threadIdx.x;
    const int b = blockIdx.y;
    const float* xb = x + (size_t)b * C * HW + q;
    float s = 0.f;
#pragma unroll 8
    for (int c = 0; c < C; ++c) {
        float v = xb[(size_t)c * HW];
        s += v * v;
    }
    float n = fmaxf(sqrtf(s), 1e-8f);
    norm[b * HW + q] = n;
    rnorm[b * HW + q] = 1.f / n;
}

// ---------------- Kernel 2: cast W to bf16 ----------------
__global__ __launch_bounds__(256) void castw_kernel(const float* __restrict__ w,
                                                    unsigned short* __restrict__ wb) {
    int i = (blockIdx.x * 256 + threadIdx.x) * 4;
    float4 v = *(const float4*)(w + i);
    unsigned long long pk = (unsigned long long)f2bf(v.x) |
                            ((unsigned long long)f2bf(v.y) << 16) |
                            ((unsigned long long)f2bf(v.z) << 32) |
                            ((unsigned long long)f2bf(v.w) << 48);
    *(unsigned long long*)(wb + i) = pk;
}

// ---------------- Kernel 3: transpose + normalize + bf16 cast ----------------
// x[b][c][q] -> xnT[b][q][c] (bf16, * rnorm[q])
__global__ __launch_bounds__(256) void prep_kernel(const float* __restrict__ x,
                                                   const float* __restrict__ rnorm,
                                                   unsigned short* __restrict__ xnT) {
    __shared__ float tile[64][65];
    const int t = threadIdx.x;
    const int q0 = blockIdx.x * 64, c0 = blockIdx.y * 64, b = blockIdx.z;
    const float* xb = x + ((size_t)b * C + c0) * HW + q0;
#pragma unroll
    for (int p = 0; p < 16; ++p) {
        int cc = p * 4 + (t >> 6);
        int qq = t & 63;
        tile[cc][qq] = xb[(size_t)cc * HW + qq];
    }
    __syncthreads();
    const float* rb = rnorm + b * HW + q0;
#pragma unroll
    for (int p = 0; p < 16; ++p) {
        int qq = p * 4 + (t >> 6);
        int cc = t & 63;
        float v = tile[cc][qq];
        float rn = rb[qq];
        xnT[((size_t)b * HW + q0 + qq) * C + c0 + cc] = f2bf(v * rn);
    }
}

// ---------------- Kernel 4: t[b][o][k] = (sum_c W[o][c]*xn[b][k][c])*norm[k]+bias[o]
// 128x128 MFMA tile, 4 waves, BK=64, global_load_lds + involutive swizzle.
__global__ __launch_bounds__(256) void tgemm_kernel(
    const unsigned short* __restrict__ A,   // W bf16 [256][256]
    const unsigned short* __restrict__ Bm,  // xnT [b][k][c]
    unsigned short* __restrict__ Cb,        // t [b][o][k]
    const float* __restrict__ bias, const float* __restrict__ norm) {
    __shared__ unsigned short Asub[128 * 64];
    __shared__ unsigned short Bsub[128 * 64];
    const int t = threadIdx.x;
    const int bz = blockIdx.z;
    const int m0 = blockIdx.y * 128, n0 = blockIdx.x * 128;

    const int ug = ((t & 7) ^ ((t >> 3) & 7)) * 16;
    const char* gA = (const char*)A + (size_t)(m0 + (t >> 3)) * (C * 2) + ug;
    const char* gB = (const char*)(Bm + (size_t)bz * HW * C) +
                     (size_t)(n0 + (t >> 3)) * (C * 2) + ug;
    char* lA = (char*)Asub + t * 16;
    char* lB = (char*)Bsub + t * 16;
    const int rowStep = 32 * C * 2;

    const int lane = t & 63;
    const int wid = t >> 6;
    const int wr = wid >> 1, wc = wid & 1;
    const int lr = lane & 15, hi = lane >> 4;
    int rowA[4], rowB[4], sb[2];
#pragma unroll
    for (int i = 0; i < 4; ++i) rowA[i] = (wr * 64 + i * 16 + lr) * 128;
#pragma unroll
    for (int j = 0; j < 4; ++j) rowB[j] = (wc * 64 + j * 16 + lr) * 128;
#pragma unroll
    for (int kk = 0; kk < 2; ++kk) sb[kk] = ((hi + 4 * kk) ^ (lr & 7)) * 16;

    f32x4 acc[4][4];
#pragma unroll
    for (int i = 0; i < 4; ++i)
#pragma unroll
        for (int j = 0; j < 4; ++j) acc[i][j] = (f32x4)(0.f);

#pragma unroll
    for (int p = 0; p < 4; ++p) {
        gload16(gA + p * rowStep, lA + p * 4096);
        gload16(gB + p * rowStep, lB + p * 4096);
    }
    for (int ks = 0; ks < 4; ++ks) {  // K = C = 256, BK = 64
        __syncthreads();
#pragma unroll
        for (int kk = 0; kk < 2; ++kk) {
            bf16x8 av[4], bv[4];
#pragma unroll
            for (int i = 0; i < 4; ++i)
                av[i] = *(const bf16x8*)((const char*)Asub + rowA[i] + sb[kk]);
#pragma unroll
            for (int j = 0; j < 4; ++j)
                bv[j] = *(const bf16x8*)((const char*)Bsub + rowB[j] + sb[kk]);
#pragma unroll
            for (int i = 0; i < 4; ++i)
#pragma unroll
                for (int j = 0; j < 4; ++j)
                    acc[i][j] = __builtin_amdgcn_mfma_f32_16x16x32_bf16(
                        av[i], bv[j], acc[i][j], 0, 0, 0);
        }
        __syncthreads();
        if (ks + 1 < 4) {
            const char* gA2 = gA + (size_t)(ks + 1) * 128;
            const char* gB2 = gB + (size_t)(ks + 1) * 128;
#pragma unroll
            for (int p = 0; p < 4; ++p) {
                gload16(gA2 + p * rowStep, lA + p * 4096);
                gload16(gB2 + p * rowStep, lB + p * 4096);
            }
        }
    }
    const int mb = m0 + wr * 64 + hi * 4;
    const int nb = n0 + wc * 64 + lr;
    unsigned short* Cp = Cb + (size_t)bz * C * HW;
    float nrm[4];
#pragma unroll
    for (int j = 0; j < 4; ++j) nrm[j] = norm[bz * HW + nb + j * 16];
#pragma unroll
    for (int i = 0; i < 4; ++i)
#pragma unroll
        for (int r = 0; r < 4; ++r) {
            int m = mb + i * 16 + r;
            float bbv = bias[m];
#pragma unroll
            for (int j = 0; j < 4; ++j)
                Cp[(size_t)m * HW + nb + j * 16] = f2bf(acc[i][j][r] * nrm[j] + bbv);
        }
}

// ---------------- Kernel 5: fused flash sim+aggregate ----------------
// Per block (b, 128-q tile): out[c][q] = sum_k relu(xn_q . xn_k)^2 * t[c][k]
// 512 threads / 8 waves. S tile lives only in LDS.
__global__ __launch_bounds__(512, 2) void fused_kernel(
    const unsigned short* __restrict__ xnT,  // [b][q][c] bf16
    const unsigned short* __restrict__ tb,   // [b][c][k] bf16
    float* __restrict__ out) {
    __shared__ unsigned short XQ[128 * 256];  // 64K [q][c], slot swz ^(q&15)
    __shared__ unsigned short XK[128 * 64];   // 16K [k][c-chunk], swz ^(k&7)
    __shared__ unsigned short SS[128 * 128];  // 32K [q][k], swz ^(q&15)
    __shared__ unsigned short TT[256 * 64];   // 32K [c][k-chunk], swz ^(c&7)
    const int t = threadIdx.x;
    const int b = blockIdx.y;
    const int qg0 = blockIdx.x * 128;
    const int lane = t & 63;
    const int wid = t >> 6;
    const int lr = lane & 15, hi = lane >> 4;

    const char* xq_g = (const char*)(xnT + ((size_t)b * HW + qg0) * C);
    const char* xk_gb = (const char*)(xnT + (size_t)b * HW * C);
    const char* t_gb = (const char*)(tb + (size_t)b * C * HW);

    // prologue: stage XQ (64KB, resident): dest linear, source slot pre-swizzled
#pragma unroll
    for (int p = 0; p < 8; ++p) {
        int u = p * 512 + t;
        int q = u >> 5, s = u & 31;
        int sp = (s & 16) | ((s & 15) ^ (q & 15));
        gload16(xq_g + (size_t)q * 512 + sp * 16, (char*)XQ + (size_t)u * 16);
    }

    const int qa = wid >> 1, ka = wid & 1;  // phase A: q-quarter(32), k-half(64)
    const int cb4 = wid >> 1, qb = wid & 1; // phase B: c-quarter(64), q-half(64)

    f32x4 oacc[4][4];
#pragma unroll
    for (int i = 0; i < 4; ++i)
#pragma unroll
        for (int j = 0; j < 4; ++j) oacc[i][j] = (f32x4)(0.f);

    for (int kt = 0; kt < 8; ++kt) {
        const int kg0 = kt * 128;
        f32x4 sacc[4][2];
#pragma unroll
        for (int i = 0; i < 4; ++i)
#pragma unroll
            for (int j = 0; j < 2; ++j) sacc[i][j] = (f32x4)(0.f);

        // ---- phase A: S' = xn_k . xn_q over 4 c-chunks of 64 ----
        for (int cch = 0; cch < 4; ++cch) {
            __syncthreads();  // previous readers of XK (and TT at cch==0) done
#pragma unroll
            for (int p = 0; p < 2; ++p) {  // stage XK chunk [128][64]
                int u = p * 512 + t;
                int k = u >> 3, s = u & 7;
                int sp = s ^ (k & 7);
                gload16(xk_gb + (size_t)(kg0 + k) * 512 + cch * 128 + sp * 16,
                        (char*)XK + (size_t)u * 16);
            }
            if (cch == 0) {  // stage TT chunk 0 early (consumed in phase B)
#pragma unroll
                for (int p = 0; p < 4; ++p) {
                    int u = p * 512 + t;
                    int c = u >> 3, s = u & 7;
                    int sp = s ^ (c & 7);
                    gload16(t_gb + (size_t)c * 2048 + kg0 * 2 + sp * 16,
                            (char*)TT + (size_t)u * 16);
                }
            }
            __syncthreads();
#pragma unroll
            for (int cs = 0; cs < 2; ++cs) {  // two 32-wide c-steps
                bf16x8 av[4], bv[2];
#pragma unroll
                for (int i = 0; i < 4; ++i) {
                    int krow = ka * 64 + i * 16 + lr;
                    int off = (cs * 64 + hi * 16) ^ ((krow & 7) << 4);
                    av[i] = *(const bf16x8*)((const char*)XK + krow * 128 + off);
                }
#pragma unroll
                for (int j = 0; j < 2; ++j) {
                    int qrow = qa * 32 + j * 16 + lr;
                    int off = ((cch * 64 + cs * 32) * 2 + hi * 16) ^ ((qrow & 15) << 4);
                    bv[j] = *(const bf16x8*)((const char*)XQ + qrow * 512 + off);
                }
#pragma unroll
                for (int i = 0; i < 4; ++i)
#pragma unroll
                    for (int j = 0; j < 2; ++j)
                        sacc[i][j] = __builtin_amdgcn_mfma_f32_16x16x32_bf16(
                            av[i], bv[j], sacc[i][j], 0, 0, 0);
            }
        }

        // ---- relu^2 -> bf16 -> S[q][k] (packed b64, swizzled) ----
#pragma unroll
        for (int i = 0; i < 4; ++i)
#pragma unroll
            for (int j = 0; j < 2; ++j) {
                int q = qa * 32 + j * 16 + lr;
                int kb = ka * 64 + i * 16 + hi * 4;
                unsigned long long pk = 0;
#pragma unroll
                for (int r = 0; r < 4; ++r) {
                    float v = fmaxf(sacc[i][j][r], 0.f);
                    v = v * v;
                    pk |= (unsigned long long)f2bf(v) << (16 * r);
                }
                int off = (kb * 2) ^ ((q & 15) << 4);
                *(unsigned long long*)((char*)SS + q * 256 + off) = pk;
            }
        __syncthreads();

        // ---- phase B: out_acc += t . S^T, two 64-k chunks ----
#pragma unroll
        for (int tch = 0; tch < 2; ++tch) {
            if (tch == 1) {
                __syncthreads();  // chunk-0 readers done
#pragma unroll
                for (int p = 0; p < 4; ++p) {
                    int u = p * 512 + t;
                    int c = u >> 3, s = u & 7;
                    int sp = s ^ (c & 7);
                    gload16(t_gb + (size_t)c * 2048 + kg0 * 2 + 128 + sp * 16,
                            (char*)TT + (size_t)u * 16);
                }
                __syncthreads();
            }
#pragma unroll
            for (int ks = 0; ks < 2; ++ks) {
                bf16x8 av[4], bv[4];
#pragma unroll
                for (int i = 0; i < 4; ++i) {
                    int crow = cb4 * 64 + i * 16 + lr;
                    int off = (ks * 64 + hi * 16) ^ ((crow & 7) << 4);
                    av[i] = *(const bf16x8*)((const char*)TT + crow * 128 + off);
                }
#pragma unroll
                for (int j = 0; j < 4; ++j) {
                    int qrow = qb * 64 + j * 16 + lr;
                    int off = (tch * 128 + ks * 64 + hi * 16) ^ ((qrow & 15) << 4);
                    bv[j] = *(const bf16x8*)((const char*)SS + qrow * 256 + off);
                }
#pragma unroll
                for (int i = 0; i < 4; ++i)
#pragma unroll
                    for (int j = 0; j < 4; ++j)
                        oacc[i][j] = __builtin_amdgcn_mfma_f32_16x16x32_bf16(
                            av[i], bv[j], oacc[i][j], 0, 0, 0);
            }
        }
    }

    // ---- epilogue: out[b][c][qg0 + q] fp32 ----
#pragma unroll
    for (int i = 0; i < 4; ++i)
#pragma unroll
        for (int r = 0; r < 4; ++r) {
            int c = cb4 * 64 + i * 16 + hi * 4 + r;
            float* op = out + ((size_t)b * C + c) * HW + qg0 + qb * 64 + lr;
#pragma unroll
            for (int j = 0; j < 4; ++j) op[j * 16] = oacc[i][j][r];
        }
}

extern "C" void kernel_launch(void* const* d_in, const int* in_sizes, int n_in,
                              void* d_out, int out_size, void* d_ws, size_t ws_size,
                              hipStream_t stream) {
    const float* x    = (const float*)d_in[0];  // (32,256,32,32)
    const float* w    = (const float*)d_in[1];  // (256,256)
    const float* bias = (const float*)d_in[2];  // (256,)
    float* out = (float*)d_out;

    // ws: norm 128K | rnorm 128K | wbf 128K | xnT 16M | t 16M
    char* ws = (char*)d_ws;
    float* norm         = (float*)ws;
    float* rnorm        = (float*)(ws + (128 << 10));
    unsigned short* wbf = (unsigned short*)(ws + (256 << 10));
    unsigned short* xnT = (unsigned short*)(ws + (384 << 10));
    unsigned short* tb  = (unsigned short*)(ws + (384 << 10) + (16u << 20));

    hipLaunchKernelGGL(norms_kernel, dim3(HW / 256, B), dim3(256), 0, stream,
                       x, norm, rnorm);
    hipLaunchKernelGGL(castw_kernel, dim3(C * C / 1024), dim3(256), 0, stream, w, wbf);
    hipLaunchKernelGGL(prep_kernel, dim3(HW / 64, C / 64, B), dim3(256), 0, stream,
                       x, rnorm, xnT);
    hipLaunchKernelGGL(tgemm_kernel, dim3(HW / 128, C / 128, B), dim3(256), 0, stream,
                       wbf, xnT, tb, bias, norm);
    hipLaunchKernelGGL(fused_kernel, dim3(HW / 128, B), dim3(512), 0, stream,
                       xnT, tb, out);
}